// Round 9
// baseline (246.697 us; speedup 1.0000x reference)
//
#include <hip/hip_runtime.h>
#include <hip/hip_bf16.h>
#include <stdint.h>
#include <stddef.h>

// B=2, S=2048, D=1024, H=16, C=64
typedef __bf16 bf16;
typedef __bf16 bf16x4 __attribute__((ext_vector_type(4)));
typedef __bf16 bf16x8 __attribute__((ext_vector_type(8)));
typedef float f32x4 __attribute__((ext_vector_type(4)));

#define DEV __device__ __forceinline__

// async global->LDS, 16B per lane; LDS dest is wave-uniform base + lane*16
DEV void async16(const bf16* g, bf16* l) {
    __builtin_amdgcn_global_load_lds(
        (const __attribute__((address_space(1))) void*)g,
        (__attribute__((address_space(3))) void*)l,
        16, 0, 0);
}

// ---------------- conversions ----------------

__global__ void convert_x(const float* __restrict__ in, bf16* __restrict__ out, int n) {
    int i = (blockIdx.x * blockDim.x + threadIdx.x) * 4;
    if (i >= n) return;
    const float4 v = *(const float4*)(in + i);
    bf16 o4[4] = {(bf16)v.x, (bf16)v.y, (bf16)v.z, (bf16)v.w};
    *(uint2*)(out + i) = *(const uint2*)o4;
}

// all four 1024x1024 weight transposes in one launch (z = which weight)
__global__ void transpose_cvt_all(const float* __restrict__ Wq, const float* __restrict__ Wk,
                                  const float* __restrict__ Wv, const float* __restrict__ Wo,
                                  bf16* __restrict__ WqkvT, bf16* __restrict__ WoT) {
    const float* src;
    bf16* dst;
    float scale = 1.0f;
    switch (blockIdx.z) {
        case 0: src = Wq; dst = WqkvT; scale = 0.125f * 1.4426950408889634f; break;
        case 1: src = Wk; dst = WqkvT + 1024 * 1024; break;
        case 2: src = Wv; dst = WqkvT + 2 * 1024 * 1024; break;
        default: src = Wo; dst = WoT; break;
    }
    __shared__ float t[32][33];
    const int c0 = blockIdx.x * 32, r0 = blockIdx.y * 32;
    const int tx = threadIdx.x & 31, ty = threadIdx.x >> 5;  // 32x8
#pragma unroll
    for (int i = 0; i < 32; i += 8)
        t[ty + i][tx] = src[(size_t)(r0 + ty + i) * 1024 + c0 + tx];
    __syncthreads();
#pragma unroll
    for (int i = 0; i < 32; i += 8)
        dst[(size_t)(c0 + ty + i) * 1024 + r0 + tx] = (bf16)(t[tx][ty + i] * scale);
}

// ---------------- GEMM (TM=4): C[m][n] = sum_k A[m][k] * BT[n][k] ----------
// 128x128 tile, BK=64 as two BK=32 panels. If VTout != nullptr, tiles with
// n0 >= 2048 are stored TRANSPOSED to VTout[n-2048][m] (bf16) instead of C.

template <bool OUT_F32>
__global__ __launch_bounds__(256, 3) void gemm_bt(
    const bf16* __restrict__ A, const bf16* __restrict__ BT, void* __restrict__ Cout,
    int M, int N, int K, bf16* __restrict__ VTout) {
    __shared__ __attribute__((aligned(16))) bf16 As[2 * 128 * 32];
    __shared__ __attribute__((aligned(16))) bf16 Bs[2 * 128 * 32];
    const int tid = threadIdx.x;
    const int wid = tid >> 6;
    const int lane = tid & 63;
    const int quad = lane >> 4;
    const int l16 = lane & 15;
    const int wm = wid >> 1, wn = wid & 1;
    const int m0 = blockIdx.y * 128, n0 = blockIdx.x * 128;

    const int srow = wid * 32 + (lane >> 2);
    const int skcol = (lane & 3) * 8;
    const bf16* ag = A + (size_t)(m0 + srow) * K + skcol;
    const bf16* bg = BT + (size_t)(n0 + srow) * K + skcol;

    f32x4 acc[4][4];
#pragma unroll
    for (int i = 0; i < 4; ++i)
#pragma unroll
        for (int j = 0; j < 4; ++j) acc[i][j] = (f32x4){0.f, 0.f, 0.f, 0.f};

    for (int k0 = 0; k0 < K; k0 += 64) {
#pragma unroll
        for (int p = 0; p < 2; ++p) {
            async16(ag + k0 + p * 32, &As[p * 4096 + (wid * 32) * 32]);
            async16(ag + (size_t)16 * K + k0 + p * 32, &As[p * 4096 + (wid * 32 + 16) * 32]);
            async16(bg + k0 + p * 32, &Bs[p * 4096 + (wid * 32) * 32]);
            async16(bg + (size_t)16 * K + k0 + p * 32, &Bs[p * 4096 + (wid * 32 + 16) * 32]);
        }
        __syncthreads();

#pragma unroll
        for (int ks = 0; ks < 2; ++ks) {
            bf16x8 af[4], bfr[4];
#pragma unroll
            for (int mi = 0; mi < 4; ++mi)
                af[mi] = *(const bf16x8*)&As[ks * 4096 + (wm * 64 + mi * 16 + l16) * 32 + quad * 8];
#pragma unroll
            for (int ni = 0; ni < 4; ++ni)
                bfr[ni] = *(const bf16x8*)&Bs[ks * 4096 + (wn * 64 + ni * 16 + l16) * 32 + quad * 8];
#pragma unroll
            for (int mi = 0; mi < 4; ++mi)
#pragma unroll
                for (int ni = 0; ni < 4; ++ni)
                    acc[mi][ni] = __builtin_amdgcn_mfma_f32_16x16x32_bf16(
                        af[mi], bfr[ni], acc[mi][ni], 0, 0, 0);
        }
        __syncthreads();
    }

    if (VTout && n0 >= 2048) {
        // store transposed: VT[n-2048][m], pack 4 consecutive m (r) as 8B
#pragma unroll
        for (int mi = 0; mi < 4; ++mi)
#pragma unroll
            for (int ni = 0; ni < 4; ++ni) {
                bf16 pk[4] = {(bf16)acc[mi][ni][0], (bf16)acc[mi][ni][1],
                              (bf16)acc[mi][ni][2], (bf16)acc[mi][ni][3]};
                *(uint2*)&VTout[(size_t)(n0 - 2048 + wn * 64 + ni * 16 + l16) * 4096 +
                                (m0 + wm * 64 + mi * 16 + quad * 4)] = *(const uint2*)pk;
            }
        return;
    }
    if (OUT_F32) {
        float* C = (float*)Cout;
#pragma unroll
        for (int mi = 0; mi < 4; ++mi)
#pragma unroll
            for (int ni = 0; ni < 4; ++ni)
#pragma unroll
                for (int r = 0; r < 4; ++r)
                    C[(size_t)(m0 + wm * 64 + mi * 16 + quad * 4 + r) * N +
                      (n0 + wn * 64 + ni * 16 + l16)] = acc[mi][ni][r];
    } else {
        bf16* C = (bf16*)Cout;
#pragma unroll
        for (int mi = 0; mi < 4; ++mi)
#pragma unroll
            for (int ni = 0; ni < 4; ++ni)
#pragma unroll
                for (int r = 0; r < 4; ++r)
                    C[(size_t)(m0 + wm * 64 + mi * 16 + quad * 4 + r) * N +
                      (n0 + wn * 64 + ni * 16 + l16)] = (bf16)acc[mi][ni][r];
    }
}

// ---------------- GEMM (TM=2): 64x128 tile, fp32 out --------------------

__global__ __launch_bounds__(256, 4) void gemm_tm2(
    const bf16* __restrict__ A, const bf16* __restrict__ BT, float* __restrict__ C,
    int M, int N, int K) {
    __shared__ __attribute__((aligned(16))) bf16 As[2 * 64 * 32];
    __shared__ __attribute__((aligned(16))) bf16 Bs[2 * 128 * 32];
    const int tid = threadIdx.x;
    const int wid = tid >> 6;
    const int lane = tid & 63;
    const int quad = lane >> 4;
    const int l16 = lane & 15;
    const int wm = wid >> 1, wn = wid & 1;
    const int m0 = blockIdx.y * 64, n0 = blockIdx.x * 128;

    const int srowA = wid * 16 + (lane >> 2);
    const int srowB = wid * 32 + (lane >> 2);
    const int skcol = (lane & 3) * 8;
    const bf16* ag = A + (size_t)(m0 + srowA) * K + skcol;
    const bf16* bg = BT + (size_t)(n0 + srowB) * K + skcol;

    f32x4 acc[2][4];
#pragma unroll
    for (int i = 0; i < 2; ++i)
#pragma unroll
        for (int j = 0; j < 4; ++j) acc[i][j] = (f32x4){0.f, 0.f, 0.f, 0.f};

    for (int k0 = 0; k0 < K; k0 += 64) {
#pragma unroll
        for (int p = 0; p < 2; ++p) {
            async16(ag + k0 + p * 32, &As[p * 2048 + (wid * 16) * 32]);
            async16(bg + k0 + p * 32, &Bs[p * 4096 + (wid * 32) * 32]);
            async16(bg + (size_t)16 * K + k0 + p * 32, &Bs[p * 4096 + (wid * 32 + 16) * 32]);
        }
        __syncthreads();

#pragma unroll
        for (int ks = 0; ks < 2; ++ks) {
            bf16x8 af[2], bfr[4];
#pragma unroll
            for (int mi = 0; mi < 2; ++mi)
                af[mi] = *(const bf16x8*)&As[ks * 2048 + (wm * 32 + mi * 16 + l16) * 32 + quad * 8];
#pragma unroll
            for (int ni = 0; ni < 4; ++ni)
                bfr[ni] = *(const bf16x8*)&Bs[ks * 4096 + (wn * 64 + ni * 16 + l16) * 32 + quad * 8];
#pragma unroll
            for (int mi = 0; mi < 2; ++mi)
#pragma unroll
                for (int ni = 0; ni < 4; ++ni)
                    acc[mi][ni] = __builtin_amdgcn_mfma_f32_16x16x32_bf16(
                        af[mi], bfr[ni], acc[mi][ni], 0, 0, 0);
        }
        __syncthreads();
    }

#pragma unroll
    for (int mi = 0; mi < 2; ++mi)
#pragma unroll
        for (int ni = 0; ni < 4; ++ni)
#pragma unroll
            for (int r = 0; r < 4; ++r)
                C[(size_t)(m0 + wm * 32 + mi * 16 + quad * 4 + r) * N +
                  (n0 + wn * 64 + ni * 16 + l16)] = acc[mi][ni][r];
}

// ---------------- flash attention (v9) ----------------
// grid (B*H, S/128): XCD = bh%8 -> each XCD's K/V working set = 4 slices
// x 512 KB = 2 MB, L2-resident. Staging via global_load_lds width=16 into a
// SINGLE 32 KB buffer with XOR-swizzled layout (conflict-free frag reads,
// no padding needed since the swizzle lives in the per-lane GLOBAL address).
// No kr/vr staging registers -> __launch_bounds__(256,3): 3 blocks/CU.
// Compute: v6/v8 structure (Q/P register-resident, S^T trick, paired K=32
// PV, no-max softmax, exp2 with scale*log2e folded into Wq).
// LDS layouts:
//   Ks[128 rows][64 c]: row r chunk x (8 elems) holds cols (x ^ (r&7))*8..
//   Vs[64 rows(c)][128 keys]: row r group g (8 keys) holds keys (g^(r&15))*8..

__global__ __launch_bounds__(256, 3) void flash_attn(
    const bf16* __restrict__ QKV, const bf16* __restrict__ VT, bf16* __restrict__ att) {
    __shared__ __attribute__((aligned(16))) char smem[33792];
    bf16* Ks = (bf16*)smem;                 // 128*64*2 = 16384 B
    bf16* Vs = (bf16*)(smem + 16384);       // 64*128*2 = 16384 B
    float* Osc = (float*)smem;              // epilogue alias: 2 x 16 KB
    float* Lred = (float*)(smem + 32768);   // [4][64] floats

    const int tid = threadIdx.x, wid = tid >> 6, lane = tid & 63;
    const int quad = lane >> 4, l16 = lane & 15;
    const int qh = wid >> 1, kh = wid & 1;
    const int bh = blockIdx.x, qt = blockIdx.y;   // XCD = bh % 8
    const int b = bh >> 4, h = bh & 15;
    const int q0 = qt * 128;

    // ---- Q B-frags (resident): B[k=quad*8+j][n=l16] = Q[q][c] ----
    bf16x8 qf[4][2];
    {
        const bf16* qbase = QKV + (size_t)(b * 2048 + q0 + qh * 64 + l16) * 3072 + h * 64 + quad * 8;
#pragma unroll
        for (int mi = 0; mi < 4; ++mi)
#pragma unroll
            for (int ks = 0; ks < 2; ++ks)
                qf[mi][ks] = *(const bf16x8*)(qbase + (size_t)mi * 16 * 3072 + ks * 32);
    }

    // ---- staging bases (per-lane global addresses implement the swizzle) ----
    // K: wave stages rows [wid*32, +32) in 4 calls of 8 rows.
    //    lane row-in-8 = lane>>3; src col chunk = (lane&7) ^ (lane>>3).
    const int klr = lane >> 3;
    const bf16* kgl = QKV + (size_t)(b * 2048 + wid * 32 + klr) * 3072 + 1024 + h * 64 +
                      (((lane & 7) ^ klr) * 8);
    // V: wave stages rows [wid*16, +16) in 4 calls of 4 rows.
    //    lane row-in-4 = lane>>4; row&15 = p*4 + (lane>>4); src key group = (lane&15)^(row&15).
    const bf16* vgl[4];
#pragma unroll
    for (int p = 0; p < 4; ++p) {
        const int vr = p * 4 + (lane >> 4);  // row & 15
        vgl[p] = VT + (size_t)(h * 64 + wid * 16 + vr) * 4096 + b * 2048 +
                 (((lane & 15) ^ vr) * 8);
    }

    f32x4 o[4][4];
    float lsum[4];
#pragma unroll
    for (int mi = 0; mi < 4; ++mi) {
        lsum[mi] = 0.f;
#pragma unroll
        for (int ct = 0; ct < 4; ++ct) o[mi][ct] = (f32x4){0.f, 0.f, 0.f, 0.f};
    }

    for (int it = 0; it < 16; ++it) {
        __syncthreads();  // all waves done reading previous tile (nothing outstanding)

        const size_t ko = (size_t)it * 128;
#pragma unroll
        for (int p = 0; p < 4; ++p)
            async16(kgl + (ko + p * 8) * 3072, &Ks[(wid * 32 + p * 8) * 64]);
#pragma unroll
        for (int p = 0; p < 4; ++p)
            async16(vgl[p] + ko, &Vs[(wid * 16 + p * 4) * 128]);
        __syncthreads();  // vmcnt drain + barrier: tile visible to all waves

        // ---- compute: wave's 64 keys as 2 pairs of 16-key groups ----
#pragma unroll
        for (int pr = 0; pr < 2; ++pr) {
            const int kb = kh * 64 + pr * 32;  // pair base (rel key)
            const int h7 = l16 & 7;
            // K A-frags (swizzled chunks): key = kb+l16 (A) / kb+16+l16 (B)
            const bf16x8 kfA0 = *(const bf16x8*)&Ks[(kb + l16) * 64 + ((quad ^ h7) * 8)];
            const bf16x8 kfA1 = *(const bf16x8*)&Ks[(kb + l16) * 64 + (((4 + quad) ^ h7) * 8)];
            const bf16x8 kfB0 = *(const bf16x8*)&Ks[(kb + 16 + l16) * 64 + ((quad ^ h7) * 8)];
            const bf16x8 kfB1 = *(const bf16x8*)&Ks[(kb + 16 + l16) * 64 + (((4 + quad) ^ h7) * 8)];
            // V B-frags (swizzled key groups): row = ct*16+l16, row&15 = l16
            bf16x8 vf[4];
#pragma unroll
            for (int ct = 0; ct < 4; ++ct) {
                const bf16x4 lo = *(const bf16x4*)&Vs[(ct * 16 + l16) * 128 +
                                                      ((kb + quad * 4) ^ (l16 * 8))];
                const bf16x4 hi = *(const bf16x4*)&Vs[(ct * 16 + l16) * 128 +
                                                      ((kb + 16 + quad * 4) ^ (l16 * 8))];
                vf[ct] = (bf16x8){lo[0], lo[1], lo[2], lo[3], hi[0], hi[1], hi[2], hi[3]};
            }
#pragma unroll
            for (int mi = 0; mi < 4; ++mi) {
                f32x4 sA = (f32x4){0.f, 0.f, 0.f, 0.f};
                f32x4 sB = (f32x4){0.f, 0.f, 0.f, 0.f};
                sA = __builtin_amdgcn_mfma_f32_16x16x32_bf16(kfA0, qf[mi][0], sA, 0, 0, 0);
                sA = __builtin_amdgcn_mfma_f32_16x16x32_bf16(kfA1, qf[mi][1], sA, 0, 0, 0);
                sB = __builtin_amdgcn_mfma_f32_16x16x32_bf16(kfB0, qf[mi][0], sB, 0, 0, 0);
                sB = __builtin_amdgcn_mfma_f32_16x16x32_bf16(kfB1, qf[mi][1], sB, 0, 0, 0);

                const float pa0 = __builtin_amdgcn_exp2f(sA[0]);
                const float pa1 = __builtin_amdgcn_exp2f(sA[1]);
                const float pa2 = __builtin_amdgcn_exp2f(sA[2]);
                const float pa3 = __builtin_amdgcn_exp2f(sA[3]);
                const float pb0 = __builtin_amdgcn_exp2f(sB[0]);
                const float pb1 = __builtin_amdgcn_exp2f(sB[1]);
                const float pb2 = __builtin_amdgcn_exp2f(sB[2]);
                const float pb3 = __builtin_amdgcn_exp2f(sB[3]);
                lsum[mi] += ((pa0 + pa1) + (pa2 + pa3)) + ((pb0 + pb1) + (pb2 + pb3));
                const bf16x8 pf = (bf16x8){(bf16)pa0, (bf16)pa1, (bf16)pa2, (bf16)pa3,
                                           (bf16)pb0, (bf16)pb1, (bf16)pb2, (bf16)pb3};
#pragma unroll
                for (int ct = 0; ct < 4; ++ct)
                    o[mi][ct] = __builtin_amdgcn_mfma_f32_16x16x32_bf16(pf, vf[ct], o[mi][ct], 0, 0, 0);
            }
        }
    }

    // ---- epilogue: l butterfly over quads, cross-wave O reduce ----
#pragma unroll
    for (int mi = 0; mi < 4; ++mi) {
        lsum[mi] += __shfl_xor(lsum[mi], 16);
        lsum[mi] += __shfl_xor(lsum[mi], 32);
    }
    __syncthreads();  // all waves done reading Ks/Vs before Osc alias writes

    if (quad == 0) {
#pragma unroll
        for (int mi = 0; mi < 4; ++mi) Lred[wid * 64 + mi * 16 + l16] = lsum[mi];
    }
    if (kh == 1) {
        float* dst = Osc + qh * 4096;
#pragma unroll
        for (int mi = 0; mi < 4; ++mi)
#pragma unroll
            for (int ct = 0; ct < 4; ++ct)
                *(f32x4*)(dst + (mi * 4 + ct) * 256 + lane * 4) = o[mi][ct];
    }
    __syncthreads();

    if (kh == 0) {
        const float* src = Osc + qh * 4096;
#pragma unroll
        for (int mi = 0; mi < 4; ++mi)
#pragma unroll
            for (int ct = 0; ct < 4; ++ct)
                o[mi][ct] += *(const f32x4*)(src + (mi * 4 + ct) * 256 + lane * 4);
#pragma unroll
        for (int mi = 0; mi < 4; ++mi)
#pragma unroll
            for (int r = 0; r < 4; ++r) {
                const int qrow = mi * 16 + quad * 4 + r;
                const float l = Lred[(qh * 2) * 64 + qrow] + Lred[(qh * 2 + 1) * 64 + qrow];
                const float inv = 1.0f / l;
                bf16* orow = att + (size_t)(b * 2048 + q0 + qh * 64 + qrow) * 1024 + h * 64 + l16;
#pragma unroll
                for (int ct = 0; ct < 4; ++ct)
                    orow[ct * 16] = (bf16)(o[mi][ct][r] * inv);
            }
    }
}

// ---------------- launch ----------------

extern "C" void kernel_launch(void* const* d_in, const int* in_sizes, int n_in,
                              void* d_out, int out_size, void* d_ws, size_t ws_size,
                              hipStream_t stream) {
    (void)in_sizes; (void)n_in; (void)out_size; (void)ws_size;
    const float* x  = (const float*)d_in[0];
    const float* Wq = (const float*)d_in[1];
    const float* Wk = (const float*)d_in[2];
    const float* Wv = (const float*)d_in[3];
    const float* Wo = (const float*)d_in[4];

    char* ws = (char*)d_ws;
    bf16* xb    = (bf16*)(ws);                             // 8 MB  [4096][1024]
    bf16* att   = xb;                                      // alias: xb dead after QKV GEMM
    bf16* WqkvT = (bf16*)(ws + (size_t)8  * 1024 * 1024);  // 6 MB [3072][1024]
    bf16* WoT   = (bf16*)(ws + (size_t)14 * 1024 * 1024);  // 2 MB [1024][1024]
    bf16* QKV   = (bf16*)(ws + (size_t)16 * 1024 * 1024);  // 24 MB [4096][3072] (V region unused)
    bf16* VT    = (bf16*)(ws + (size_t)40 * 1024 * 1024);  // 8 MB [1024][4096]
    // total 48 MB

    const int n_x = 2 * 2048 * 1024;  // 4194304
    convert_x<<<n_x / (256 * 4), 256, 0, stream>>>(x, xb, n_x);

    // all 4 weight transposes; Wq pre-scaled by C^-0.5 * log2(e)
    transpose_cvt_all<<<dim3(32, 32, 4), 256, 0, stream>>>(Wq, Wk, Wv, Wo, WqkvT, WoT);

    // QKV = xb @ [Wq|Wk|Wv] : M=4096 N=3072 K=1024 (768 blocks = 3/CU);
    // V-tiles stored transposed straight to VT (transpose_v fused away)
    gemm_bt<false><<<dim3(3072 / 128, 4096 / 128), 256, 0, stream>>>(
        xb, WqkvT, QKV, 4096, 3072, 1024, VT);

    // attention -> att[bs][hc]; grid (bh, qt) so XCD = bh%8 (L2-local K/V)
    flash_attn<<<dim3(32, 16), 256, 0, stream>>>(QKV, VT, att);

    // out = att @ Wo : M=4096 N=1024 K=1024, fp32 out, 64x128 tile (2 blk/CU)
    gemm_tm2<<<dim3(1024 / 128, 4096 / 64), 256, 0, stream>>>(
        att, WoT, (float*)d_out, 4096, 1024, 1024);
}

// Round 10
// 176.683 us; speedup vs baseline: 1.3963x; 1.3963x over previous
//
#include <hip/hip_runtime.h>
#include <hip/hip_bf16.h>
#include <stdint.h>
#include <stddef.h>

// B=2, S=2048, D=1024, H=16, C=64
typedef __bf16 bf16;
typedef __bf16 bf16x4 __attribute__((ext_vector_type(4)));
typedef __bf16 bf16x8 __attribute__((ext_vector_type(8)));
typedef float f32x4 __attribute__((ext_vector_type(4)));

#define DEV __device__ __forceinline__

// async global->LDS, 16B per lane; LDS dest is wave-uniform base + lane*16
DEV void async16(const bf16* g, bf16* l) {
    __builtin_amdgcn_global_load_lds(
        (const __attribute__((address_space(1))) void*)g,
        (__attribute__((address_space(3))) void*)l,
        16, 0, 0);
}

// ---------------- conversions ----------------

__global__ void convert_x(const float* __restrict__ in, bf16* __restrict__ out, int n) {
    int i = (blockIdx.x * blockDim.x + threadIdx.x) * 4;
    if (i >= n) return;
    const float4 v = *(const float4*)(in + i);
    bf16 o4[4] = {(bf16)v.x, (bf16)v.y, (bf16)v.z, (bf16)v.w};
    *(uint2*)(out + i) = *(const uint2*)o4;
}

// all four 1024x1024 weight transposes in one launch (z = which weight)
__global__ void transpose_cvt_all(const float* __restrict__ Wq, const float* __restrict__ Wk,
                                  const float* __restrict__ Wv, const float* __restrict__ Wo,
                                  bf16* __restrict__ WqkvT, bf16* __restrict__ WoT) {
    const float* src;
    bf16* dst;
    float scale = 1.0f;
    switch (blockIdx.z) {
        case 0: src = Wq; dst = WqkvT; scale = 0.125f * 1.4426950408889634f; break;
        case 1: src = Wk; dst = WqkvT + 1024 * 1024; break;
        case 2: src = Wv; dst = WqkvT + 2 * 1024 * 1024; break;
        default: src = Wo; dst = WoT; break;
    }
    __shared__ float t[32][33];
    const int c0 = blockIdx.x * 32, r0 = blockIdx.y * 32;
    const int tx = threadIdx.x & 31, ty = threadIdx.x >> 5;  // 32x8
#pragma unroll
    for (int i = 0; i < 32; i += 8)
        t[ty + i][tx] = src[(size_t)(r0 + ty + i) * 1024 + c0 + tx];
    __syncthreads();
#pragma unroll
    for (int i = 0; i < 32; i += 8)
        dst[(size_t)(c0 + ty + i) * 1024 + r0 + tx] = (bf16)(t[tx][ty + i] * scale);
}

// ---------------- GEMM (TM=4): C[m][n] = sum_k A[m][k] * BT[n][k] ----------
// 128x128 tile, BK=64 as two BK=32 panels. If VTout != nullptr, tiles with
// n0 >= 2048 are stored TRANSPOSED to VTout[n-2048][m] (bf16) instead of C.

template <bool OUT_F32>
__global__ __launch_bounds__(256, 3) void gemm_bt(
    const bf16* __restrict__ A, const bf16* __restrict__ BT, void* __restrict__ Cout,
    int M, int N, int K, bf16* __restrict__ VTout) {
    __shared__ __attribute__((aligned(16))) bf16 As[2 * 128 * 32];
    __shared__ __attribute__((aligned(16))) bf16 Bs[2 * 128 * 32];
    const int tid = threadIdx.x;
    const int wid = tid >> 6;
    const int lane = tid & 63;
    const int quad = lane >> 4;
    const int l16 = lane & 15;
    const int wm = wid >> 1, wn = wid & 1;
    const int m0 = blockIdx.y * 128, n0 = blockIdx.x * 128;

    const int srow = wid * 32 + (lane >> 2);
    const int skcol = (lane & 3) * 8;
    const bf16* ag = A + (size_t)(m0 + srow) * K + skcol;
    const bf16* bg = BT + (size_t)(n0 + srow) * K + skcol;

    f32x4 acc[4][4];
#pragma unroll
    for (int i = 0; i < 4; ++i)
#pragma unroll
        for (int j = 0; j < 4; ++j) acc[i][j] = (f32x4){0.f, 0.f, 0.f, 0.f};

    for (int k0 = 0; k0 < K; k0 += 64) {
#pragma unroll
        for (int p = 0; p < 2; ++p) {
            async16(ag + k0 + p * 32, &As[p * 4096 + (wid * 32) * 32]);
            async16(ag + (size_t)16 * K + k0 + p * 32, &As[p * 4096 + (wid * 32 + 16) * 32]);
            async16(bg + k0 + p * 32, &Bs[p * 4096 + (wid * 32) * 32]);
            async16(bg + (size_t)16 * K + k0 + p * 32, &Bs[p * 4096 + (wid * 32 + 16) * 32]);
        }
        __syncthreads();

#pragma unroll
        for (int ks = 0; ks < 2; ++ks) {
            bf16x8 af[4], bfr[4];
#pragma unroll
            for (int mi = 0; mi < 4; ++mi)
                af[mi] = *(const bf16x8*)&As[ks * 4096 + (wm * 64 + mi * 16 + l16) * 32 + quad * 8];
#pragma unroll
            for (int ni = 0; ni < 4; ++ni)
                bfr[ni] = *(const bf16x8*)&Bs[ks * 4096 + (wn * 64 + ni * 16 + l16) * 32 + quad * 8];
#pragma unroll
            for (int mi = 0; mi < 4; ++mi)
#pragma unroll
                for (int ni = 0; ni < 4; ++ni)
                    acc[mi][ni] = __builtin_amdgcn_mfma_f32_16x16x32_bf16(
                        af[mi], bfr[ni], acc[mi][ni], 0, 0, 0);
        }
        __syncthreads();
    }

    if (VTout && n0 >= 2048) {
        // store transposed: VT[n-2048][m], pack 4 consecutive m (r) as 8B
#pragma unroll
        for (int mi = 0; mi < 4; ++mi)
#pragma unroll
            for (int ni = 0; ni < 4; ++ni) {
                bf16 pk[4] = {(bf16)acc[mi][ni][0], (bf16)acc[mi][ni][1],
                              (bf16)acc[mi][ni][2], (bf16)acc[mi][ni][3]};
                *(uint2*)&VTout[(size_t)(n0 - 2048 + wn * 64 + ni * 16 + l16) * 4096 +
                                (m0 + wm * 64 + mi * 16 + quad * 4)] = *(const uint2*)pk;
            }
        return;
    }
    if (OUT_F32) {
        float* C = (float*)Cout;
#pragma unroll
        for (int mi = 0; mi < 4; ++mi)
#pragma unroll
            for (int ni = 0; ni < 4; ++ni)
#pragma unroll
                for (int r = 0; r < 4; ++r)
                    C[(size_t)(m0 + wm * 64 + mi * 16 + quad * 4 + r) * N +
                      (n0 + wn * 64 + ni * 16 + l16)] = acc[mi][ni][r];
    } else {
        bf16* C = (bf16*)Cout;
#pragma unroll
        for (int mi = 0; mi < 4; ++mi)
#pragma unroll
            for (int ni = 0; ni < 4; ++ni)
#pragma unroll
                for (int r = 0; r < 4; ++r)
                    C[(size_t)(m0 + wm * 64 + mi * 16 + quad * 4 + r) * N +
                      (n0 + wn * 64 + ni * 16 + l16)] = (bf16)acc[mi][ni][r];
    }
}

// ---------------- GEMM (TM=2): 64x128 tile, fp32 out --------------------

__global__ __launch_bounds__(256, 4) void gemm_tm2(
    const bf16* __restrict__ A, const bf16* __restrict__ BT, float* __restrict__ C,
    int M, int N, int K) {
    __shared__ __attribute__((aligned(16))) bf16 As[2 * 64 * 32];
    __shared__ __attribute__((aligned(16))) bf16 Bs[2 * 128 * 32];
    const int tid = threadIdx.x;
    const int wid = tid >> 6;
    const int lane = tid & 63;
    const int quad = lane >> 4;
    const int l16 = lane & 15;
    const int wm = wid >> 1, wn = wid & 1;
    const int m0 = blockIdx.y * 64, n0 = blockIdx.x * 128;

    const int srowA = wid * 16 + (lane >> 2);
    const int srowB = wid * 32 + (lane >> 2);
    const int skcol = (lane & 3) * 8;
    const bf16* ag = A + (size_t)(m0 + srowA) * K + skcol;
    const bf16* bg = BT + (size_t)(n0 + srowB) * K + skcol;

    f32x4 acc[2][4];
#pragma unroll
    for (int i = 0; i < 2; ++i)
#pragma unroll
        for (int j = 0; j < 4; ++j) acc[i][j] = (f32x4){0.f, 0.f, 0.f, 0.f};

    for (int k0 = 0; k0 < K; k0 += 64) {
#pragma unroll
        for (int p = 0; p < 2; ++p) {
            async16(ag + k0 + p * 32, &As[p * 2048 + (wid * 16) * 32]);
            async16(bg + k0 + p * 32, &Bs[p * 4096 + (wid * 32) * 32]);
            async16(bg + (size_t)16 * K + k0 + p * 32, &Bs[p * 4096 + (wid * 32 + 16) * 32]);
        }
        __syncthreads();

#pragma unroll
        for (int ks = 0; ks < 2; ++ks) {
            bf16x8 af[2], bfr[4];
#pragma unroll
            for (int mi = 0; mi < 2; ++mi)
                af[mi] = *(const bf16x8*)&As[ks * 2048 + (wm * 32 + mi * 16 + l16) * 32 + quad * 8];
#pragma unroll
            for (int ni = 0; ni < 4; ++ni)
                bfr[ni] = *(const bf16x8*)&Bs[ks * 4096 + (wn * 64 + ni * 16 + l16) * 32 + quad * 8];
#pragma unroll
            for (int mi = 0; mi < 2; ++mi)
#pragma unroll
                for (int ni = 0; ni < 4; ++ni)
                    acc[mi][ni] = __builtin_amdgcn_mfma_f32_16x16x32_bf16(
                        af[mi], bfr[ni], acc[mi][ni], 0, 0, 0);
        }
        __syncthreads();
    }

#pragma unroll
    for (int mi = 0; mi < 2; ++mi)
#pragma unroll
        for (int ni = 0; ni < 4; ++ni)
#pragma unroll
            for (int r = 0; r < 4; ++r)
                C[(size_t)(m0 + wm * 32 + mi * 16 + quad * 4 + r) * N +
                  (n0 + wn * 64 + ni * 16 + l16)] = acc[mi][ni][r];
}

// ---------------- flash attention (v10 = v6 exact + XCD-local grid) ------
// v6 (best measured: 48.3 us): single-buffer LDS, register prefetch,
// stage -> barrier -> prefetch -> compute -> barrier; (256,2); Q/P register
// resident, S^T trick, paired K=32 PV, no-max softmax (scale*log2e in Wq).
// ONLY change vs v6: grid is (bh, qt) so XCD = bh%8 -> each XCD's K/V
// working set = 4 slices x 512 KB = 2 MB, L2-resident (verified in v9:
// FETCH 74->56 MB). No structural changes (m131-141: barrier tweaks are noise).

__global__ __launch_bounds__(256, 2) void flash_attn(
    const bf16* __restrict__ QKV, const bf16* __restrict__ VT, bf16* __restrict__ att) {
    constexpr int LDK = 72;   // Ks stride: frag-read banks 4*(l16+quad) uniform
    constexpr int LDV = 136;  // Vs stride: b64 reads 2-way (free), writes 8-phase
    __shared__ __attribute__((aligned(16))) char smem[36864];
    bf16* Ks = (bf16*)smem;                // [128][72]  = 18432 B
    bf16* Vs = (bf16*)(smem + 18432);      // [64][136]  = 17408 B -> 35840
    float* Osc = (float*)smem;             // epilogue alias: 2 regions x 16 KB
    float* Lred = (float*)(smem + 32768);  // [4][64] floats

    const int tid = threadIdx.x, wid = tid >> 6, lane = tid & 63;
    const int quad = lane >> 4, l16 = lane & 15;
    const int qh = wid >> 1, kh = wid & 1;
    const int bh = blockIdx.x, qt = blockIdx.y;   // XCD = bh % 8 (L2-local K/V)
    const int b = bh >> 4, h = bh & 15;
    const int q0 = qt * 128;

    // ---- Q B-frags (resident): B[k=quad*8+j][n=l16] = Q[q][c] ----
    bf16x8 qf[4][2];
    {
        const bf16* qbase = QKV + (size_t)(b * 2048 + q0 + qh * 64 + l16) * 3072 + h * 64 + quad * 8;
#pragma unroll
        for (int mi = 0; mi < 4; ++mi)
#pragma unroll
            for (int ks = 0; ks < 2; ++ks)
                qf[mi][ks] = *(const bf16x8*)(qbase + (size_t)mi * 16 * 3072 + ks * 32);
    }

    // staging geometry (coalesced): K 128 rows x 128 B, V 64 rows x 256 B
    const int krow = tid >> 3, kcol = (tid & 7) * 8;   // 32 rows/pass, 4 passes
    const int vrow = tid >> 4, vcol = (tid & 15) * 8;  // 16 rows/pass, 4 passes
    const bf16* kg = QKV + (size_t)(b * 2048 + krow) * 3072 + 1024 + h * 64 + kcol;
    const bf16* vg = VT + (size_t)(h * 64 + vrow) * 4096 + b * 2048 + vcol;

    bf16x8 kr[4], vr[4];
#pragma unroll
    for (int p = 0; p < 4; ++p) {
        kr[p] = *(const bf16x8*)(kg + (size_t)(32 * p) * 3072);
        vr[p] = *(const bf16x8*)(vg + (size_t)(16 * p) * 4096);
    }

    f32x4 o[4][4];
    float lsum[4];
#pragma unroll
    for (int mi = 0; mi < 4; ++mi) {
        lsum[mi] = 0.f;
#pragma unroll
        for (int ct = 0; ct < 4; ++ct) o[mi][ct] = (f32x4){0.f, 0.f, 0.f, 0.f};
    }

    for (int it = 0; it < 16; ++it) {
        // ---- stage prefetched regs -> LDS ----
#pragma unroll
        for (int p = 0; p < 4; ++p) {
            *(bf16x8*)&Ks[(32 * p + krow) * LDK + kcol] = kr[p];
            *(bf16x8*)&Vs[(16 * p + vrow) * LDV + vcol] = vr[p];
        }
        __syncthreads();

        // ---- prefetch next big-iter (hidden behind compute phase) ----
        if (it < 15) {
            const size_t ko = (size_t)(it + 1) * 128;
#pragma unroll
            for (int p = 0; p < 4; ++p) {
                kr[p] = *(const bf16x8*)(kg + (ko + 32 * p) * 3072);
                vr[p] = *(const bf16x8*)(vg + (size_t)(16 * p) * 4096 + ko);
            }
        }

        // ---- compute: wave's 64 keys as 2 pairs of 16-key groups ----
#pragma unroll
        for (int pr = 0; pr < 2; ++pr) {
            const int kb = kh * 64 + pr * 32;  // pair base (rel key)
            const bf16x8 kfA0 = *(const bf16x8*)&Ks[(kb + l16) * LDK + quad * 8];
            const bf16x8 kfA1 = *(const bf16x8*)&Ks[(kb + l16) * LDK + 32 + quad * 8];
            const bf16x8 kfB0 = *(const bf16x8*)&Ks[(kb + 16 + l16) * LDK + quad * 8];
            const bf16x8 kfB1 = *(const bf16x8*)&Ks[(kb + 16 + l16) * LDK + 32 + quad * 8];
            bf16x8 vf[4];
#pragma unroll
            for (int ct = 0; ct < 4; ++ct) {
                const bf16x4 lo = *(const bf16x4*)&Vs[(ct * 16 + l16) * LDV + kb + quad * 4];
                const bf16x4 hi = *(const bf16x4*)&Vs[(ct * 16 + l16) * LDV + kb + 16 + quad * 4];
                vf[ct] = (bf16x8){lo[0], lo[1], lo[2], lo[3], hi[0], hi[1], hi[2], hi[3]};
            }
#pragma unroll
            for (int mi = 0; mi < 4; ++mi) {
                f32x4 sA = (f32x4){0.f, 0.f, 0.f, 0.f};
                f32x4 sB = (f32x4){0.f, 0.f, 0.f, 0.f};
                sA = __builtin_amdgcn_mfma_f32_16x16x32_bf16(kfA0, qf[mi][0], sA, 0, 0, 0);
                sA = __builtin_amdgcn_mfma_f32_16x16x32_bf16(kfA1, qf[mi][1], sA, 0, 0, 0);
                sB = __builtin_amdgcn_mfma_f32_16x16x32_bf16(kfB0, qf[mi][0], sB, 0, 0, 0);
                sB = __builtin_amdgcn_mfma_f32_16x16x32_bf16(kfB1, qf[mi][1], sB, 0, 0, 0);

                const float pa0 = __builtin_amdgcn_exp2f(sA[0]);
                const float pa1 = __builtin_amdgcn_exp2f(sA[1]);
                const float pa2 = __builtin_amdgcn_exp2f(sA[2]);
                const float pa3 = __builtin_amdgcn_exp2f(sA[3]);
                const float pb0 = __builtin_amdgcn_exp2f(sB[0]);
                const float pb1 = __builtin_amdgcn_exp2f(sB[1]);
                const float pb2 = __builtin_amdgcn_exp2f(sB[2]);
                const float pb3 = __builtin_amdgcn_exp2f(sB[3]);
                lsum[mi] += ((pa0 + pa1) + (pa2 + pa3)) + ((pb0 + pb1) + (pb2 + pb3));
                const bf16x8 pf = (bf16x8){(bf16)pa0, (bf16)pa1, (bf16)pa2, (bf16)pa3,
                                           (bf16)pb0, (bf16)pb1, (bf16)pb2, (bf16)pb3};
#pragma unroll
                for (int ct = 0; ct < 4; ++ct)
                    o[mi][ct] = __builtin_amdgcn_mfma_f32_16x16x32_bf16(pf, vf[ct], o[mi][ct], 0, 0, 0);
            }
        }
        __syncthreads();
    }

    // ---- epilogue: l butterfly over quads, cross-wave O reduce ----
#pragma unroll
    for (int mi = 0; mi < 4; ++mi) {
        lsum[mi] += __shfl_xor(lsum[mi], 16);
        lsum[mi] += __shfl_xor(lsum[mi], 32);
    }
    if (quad == 0) {
#pragma unroll
        for (int mi = 0; mi < 4; ++mi) Lred[wid * 64 + mi * 16 + l16] = lsum[mi];
    }
    if (kh == 1) {
        float* dst = Osc + qh * 4096;
#pragma unroll
        for (int mi = 0; mi < 4; ++mi)
#pragma unroll
            for (int ct = 0; ct < 4; ++ct)
                *(f32x4*)(dst + (mi * 4 + ct) * 256 + lane * 4) = o[mi][ct];
    }
    __syncthreads();

    if (kh == 0) {
        const float* src = Osc + qh * 4096;
#pragma unroll
        for (int mi = 0; mi < 4; ++mi)
#pragma unroll
            for (int ct = 0; ct < 4; ++ct)
                o[mi][ct] += *(const f32x4*)(src + (mi * 4 + ct) * 256 + lane * 4);
#pragma unroll
        for (int mi = 0; mi < 4; ++mi)
#pragma unroll
            for (int r = 0; r < 4; ++r) {
                const int qrow = mi * 16 + quad * 4 + r;
                const float l = Lred[(qh * 2) * 64 + qrow] + Lred[(qh * 2 + 1) * 64 + qrow];
                const float inv = 1.0f / l;
                bf16* orow = att + (size_t)(b * 2048 + q0 + qh * 64 + qrow) * 1024 + h * 64 + l16;
#pragma unroll
                for (int ct = 0; ct < 4; ++ct)
                    orow[ct * 16] = (bf16)(o[mi][ct][r] * inv);
            }
    }
}

// ---------------- launch ----------------

extern "C" void kernel_launch(void* const* d_in, const int* in_sizes, int n_in,
                              void* d_out, int out_size, void* d_ws, size_t ws_size,
                              hipStream_t stream) {
    (void)in_sizes; (void)n_in; (void)out_size; (void)ws_size;
    const float* x  = (const float*)d_in[0];
    const float* Wq = (const float*)d_in[1];
    const float* Wk = (const float*)d_in[2];
    const float* Wv = (const float*)d_in[3];
    const float* Wo = (const float*)d_in[4];

    char* ws = (char*)d_ws;
    bf16* xb    = (bf16*)(ws);                             // 8 MB  [4096][1024]
    bf16* att   = xb;                                      // alias: xb dead after QKV GEMM
    bf16* WqkvT = (bf16*)(ws + (size_t)8  * 1024 * 1024);  // 6 MB [3072][1024]
    bf16* WoT   = (bf16*)(ws + (size_t)14 * 1024 * 1024);  // 2 MB [1024][1024]
    bf16* QKV   = (bf16*)(ws + (size_t)16 * 1024 * 1024);  // 24 MB [4096][3072] (V region unused)
    bf16* VT    = (bf16*)(ws + (size_t)40 * 1024 * 1024);  // 8 MB [1024][4096]
    // total 48 MB

    const int n_x = 2 * 2048 * 1024;  // 4194304
    convert_x<<<n_x / (256 * 4), 256, 0, stream>>>(x, xb, n_x);

    // all 4 weight transposes; Wq pre-scaled by C^-0.5 * log2(e)
    transpose_cvt_all<<<dim3(32, 32, 4), 256, 0, stream>>>(Wq, Wk, Wv, Wo, WqkvT, WoT);

    // QKV = xb @ [Wq|Wk|Wv] : M=4096 N=3072 K=1024 (768 blocks = 3/CU);
    // V-tiles stored transposed straight to VT (transpose_v fused away)
    gemm_bt<false><<<dim3(3072 / 128, 4096 / 128), 256, 0, stream>>>(
        xb, WqkvT, QKV, 4096, 3072, 1024, VT);

    // attention -> att[bs][hc]; grid (bh, qt) so XCD = bh%8 (L2-local K/V)
    flash_attn<<<dim3(32, 16), 256, 0, stream>>>(QKV, VT, att);

    // out = att @ Wo : M=4096 N=1024 K=1024, fp32 out, 64x128 tile (2 blk/CU)
    gemm_tm2<<<dim3(1024 / 128, 4096 / 64), 256, 0, stream>>>(
        att, WoT, (float*)d_out, 4096, 1024, 1024);
}

// Round 11
// 173.317 us; speedup vs baseline: 1.4234x; 1.0194x over previous
//
#include <hip/hip_runtime.h>
#include <hip/hip_bf16.h>
#include <stdint.h>
#include <stddef.h>

// B=2, S=2048, D=1024, H=16, C=64
typedef __bf16 bf16;
typedef __bf16 bf16x4 __attribute__((ext_vector_type(4)));
typedef __bf16 bf16x8 __attribute__((ext_vector_type(8)));
typedef float f32x4 __attribute__((ext_vector_type(4)));

#define DEV __device__ __forceinline__

// async global->LDS, 16B per lane; LDS dest is wave-uniform base + lane*16
DEV void async16(const bf16* g, bf16* l) {
    __builtin_amdgcn_global_load_lds(
        (const __attribute__((address_space(1))) void*)g,
        (__attribute__((address_space(3))) void*)l,
        16, 0, 0);
}

// pack two f32 -> two bf16 (truncation) in ONE v_perm_b32.
// Truncation bias cancels in P/l since l is computed from the same packed P.
DEV uint32_t pktrunc(float lo, float hi) {
    return __builtin_amdgcn_perm(__builtin_bit_cast(uint32_t, hi),
                                 __builtin_bit_cast(uint32_t, lo), 0x07060302u);
}

// ---------------- prep: x->bf16 convert (z=4) + 4 weight transposes (z=0..3) --

__global__ void prep(const float* __restrict__ x,
                     const float* __restrict__ Wq, const float* __restrict__ Wk,
                     const float* __restrict__ Wv, const float* __restrict__ Wo,
                     bf16* __restrict__ xb, bf16* __restrict__ WqkvT,
                     bf16* __restrict__ WoT) {
    __shared__ float t[32][33];
    if (blockIdx.z == 4) {
        const int bid = blockIdx.y * 32 + blockIdx.x;
#pragma unroll
        for (int i = 0; i < 4; ++i) {
            const int idx = ((bid * 4 + i) * 256 + threadIdx.x) * 4;
            const float4 v = *(const float4*)(x + idx);
            bf16 o4[4] = {(bf16)v.x, (bf16)v.y, (bf16)v.z, (bf16)v.w};
            *(uint2*)(xb + idx) = *(const uint2*)o4;
        }
        return;
    }
    const float* src;
    bf16* dst;
    float scale = 1.0f;
    switch (blockIdx.z) {
        case 0: src = Wq; dst = WqkvT; scale = 0.125f * 1.4426950408889634f; break;
        case 1: src = Wk; dst = WqkvT + 1024 * 1024; break;
        case 2: src = Wv; dst = WqkvT + 2 * 1024 * 1024; break;
        default: src = Wo; dst = WoT; break;
    }
    const int c0 = blockIdx.x * 32, r0 = blockIdx.y * 32;
    const int tx = threadIdx.x & 31, ty = threadIdx.x >> 5;  // 32x8
#pragma unroll
    for (int i = 0; i < 32; i += 8)
        t[ty + i][tx] = src[(size_t)(r0 + ty + i) * 1024 + c0 + tx];
    __syncthreads();
#pragma unroll
    for (int i = 0; i < 32; i += 8)
        dst[(size_t)(c0 + ty + i) * 1024 + r0 + tx] = (bf16)(t[tx][ty + i] * scale);
}

// ---------------- GEMM (TM=4): C[m][n] = sum_k A[m][k] * BT[n][k] ----------
// 128x128 tile, BK=64 as two BK=32 panels. If VTout != nullptr, tiles with
// n0 >= 2048 are stored TRANSPOSED to VTout[n-2048][m] (bf16) instead of C.

template <bool OUT_F32>
__global__ __launch_bounds__(256, 3) void gemm_bt(
    const bf16* __restrict__ A, const bf16* __restrict__ BT, void* __restrict__ Cout,
    int M, int N, int K, bf16* __restrict__ VTout) {
    __shared__ __attribute__((aligned(16))) bf16 As[2 * 128 * 32];
    __shared__ __attribute__((aligned(16))) bf16 Bs[2 * 128 * 32];
    const int tid = threadIdx.x;
    const int wid = tid >> 6;
    const int lane = tid & 63;
    const int quad = lane >> 4;
    const int l16 = lane & 15;
    const int wm = wid >> 1, wn = wid & 1;
    const int m0 = blockIdx.y * 128, n0 = blockIdx.x * 128;

    const int srow = wid * 32 + (lane >> 2);
    const int skcol = (lane & 3) * 8;
    const bf16* ag = A + (size_t)(m0 + srow) * K + skcol;
    const bf16* bg = BT + (size_t)(n0 + srow) * K + skcol;

    f32x4 acc[4][4];
#pragma unroll
    for (int i = 0; i < 4; ++i)
#pragma unroll
        for (int j = 0; j < 4; ++j) acc[i][j] = (f32x4){0.f, 0.f, 0.f, 0.f};

    for (int k0 = 0; k0 < K; k0 += 64) {
#pragma unroll
        for (int p = 0; p < 2; ++p) {
            async16(ag + k0 + p * 32, &As[p * 4096 + (wid * 32) * 32]);
            async16(ag + (size_t)16 * K + k0 + p * 32, &As[p * 4096 + (wid * 32 + 16) * 32]);
            async16(bg + k0 + p * 32, &Bs[p * 4096 + (wid * 32) * 32]);
            async16(bg + (size_t)16 * K + k0 + p * 32, &Bs[p * 4096 + (wid * 32 + 16) * 32]);
        }
        __syncthreads();

#pragma unroll
        for (int ks = 0; ks < 2; ++ks) {
            bf16x8 af[4], bfr[4];
#pragma unroll
            for (int mi = 0; mi < 4; ++mi)
                af[mi] = *(const bf16x8*)&As[ks * 4096 + (wm * 64 + mi * 16 + l16) * 32 + quad * 8];
#pragma unroll
            for (int ni = 0; ni < 4; ++ni)
                bfr[ni] = *(const bf16x8*)&Bs[ks * 4096 + (wn * 64 + ni * 16 + l16) * 32 + quad * 8];
#pragma unroll
            for (int mi = 0; mi < 4; ++mi)
#pragma unroll
                for (int ni = 0; ni < 4; ++ni)
                    acc[mi][ni] = __builtin_amdgcn_mfma_f32_16x16x32_bf16(
                        af[mi], bfr[ni], acc[mi][ni], 0, 0, 0);
        }
        __syncthreads();
    }

    if (VTout && n0 >= 2048) {
        // store transposed: VT[n-2048][m], pack 4 consecutive m (r) as 8B
#pragma unroll
        for (int mi = 0; mi < 4; ++mi)
#pragma unroll
            for (int ni = 0; ni < 4; ++ni) {
                bf16 pk[4] = {(bf16)acc[mi][ni][0], (bf16)acc[mi][ni][1],
                              (bf16)acc[mi][ni][2], (bf16)acc[mi][ni][3]};
                *(uint2*)&VTout[(size_t)(n0 - 2048 + wn * 64 + ni * 16 + l16) * 4096 +
                                (m0 + wm * 64 + mi * 16 + quad * 4)] = *(const uint2*)pk;
            }
        return;
    }
    if (OUT_F32) {
        float* C = (float*)Cout;
#pragma unroll
        for (int mi = 0; mi < 4; ++mi)
#pragma unroll
            for (int ni = 0; ni < 4; ++ni)
#pragma unroll
                for (int r = 0; r < 4; ++r)
                    C[(size_t)(m0 + wm * 64 + mi * 16 + quad * 4 + r) * N +
                      (n0 + wn * 64 + ni * 16 + l16)] = acc[mi][ni][r];
    } else {
        bf16* C = (bf16*)Cout;
#pragma unroll
        for (int mi = 0; mi < 4; ++mi)
#pragma unroll
            for (int ni = 0; ni < 4; ++ni)
#pragma unroll
                for (int r = 0; r < 4; ++r)
                    C[(size_t)(m0 + wm * 64 + mi * 16 + quad * 4 + r) * N +
                      (n0 + wn * 64 + ni * 16 + l16)] = (bf16)acc[mi][ni][r];
    }
}

// ---------------- GEMM (TM=2): 64x128 tile, fp32 out --------------------

__global__ __launch_bounds__(256, 4) void gemm_tm2(
    const bf16* __restrict__ A, const bf16* __restrict__ BT, float* __restrict__ C,
    int M, int N, int K) {
    __shared__ __attribute__((aligned(16))) bf16 As[2 * 64 * 32];
    __shared__ __attribute__((aligned(16))) bf16 Bs[2 * 128 * 32];
    const int tid = threadIdx.x;
    const int wid = tid >> 6;
    const int lane = tid & 63;
    const int quad = lane >> 4;
    const int l16 = lane & 15;
    const int wm = wid >> 1, wn = wid & 1;
    const int m0 = blockIdx.y * 64, n0 = blockIdx.x * 128;

    const int srowA = wid * 16 + (lane >> 2);
    const int srowB = wid * 32 + (lane >> 2);
    const int skcol = (lane & 3) * 8;
    const bf16* ag = A + (size_t)(m0 + srowA) * K + skcol;
    const bf16* bg = BT + (size_t)(n0 + srowB) * K + skcol;

    f32x4 acc[2][4];
#pragma unroll
    for (int i = 0; i < 2; ++i)
#pragma unroll
        for (int j = 0; j < 4; ++j) acc[i][j] = (f32x4){0.f, 0.f, 0.f, 0.f};

    for (int k0 = 0; k0 < K; k0 += 64) {
#pragma unroll
        for (int p = 0; p < 2; ++p) {
            async16(ag + k0 + p * 32, &As[p * 2048 + (wid * 16) * 32]);
            async16(bg + k0 + p * 32, &Bs[p * 4096 + (wid * 32) * 32]);
            async16(bg + (size_t)16 * K + k0 + p * 32, &Bs[p * 4096 + (wid * 32 + 16) * 32]);
        }
        __syncthreads();

#pragma unroll
        for (int ks = 0; ks < 2; ++ks) {
            bf16x8 af[2], bfr[4];
#pragma unroll
            for (int mi = 0; mi < 2; ++mi)
                af[mi] = *(const bf16x8*)&As[ks * 2048 + (wm * 32 + mi * 16 + l16) * 32 + quad * 8];
#pragma unroll
            for (int ni = 0; ni < 4; ++ni)
                bfr[ni] = *(const bf16x8*)&Bs[ks * 4096 + (wn * 64 + ni * 16 + l16) * 32 + quad * 8];
#pragma unroll
            for (int mi = 0; mi < 2; ++mi)
#pragma unroll
                for (int ni = 0; ni < 4; ++ni)
                    acc[mi][ni] = __builtin_amdgcn_mfma_f32_16x16x32_bf16(
                        af[mi], bfr[ni], acc[mi][ni], 0, 0, 0);
        }
        __syncthreads();
    }

#pragma unroll
    for (int mi = 0; mi < 2; ++mi)
#pragma unroll
        for (int ni = 0; ni < 4; ++ni)
#pragma unroll
            for (int r = 0; r < 4; ++r)
                C[(size_t)(m0 + wm * 32 + mi * 16 + quad * 4 + r) * N +
                  (n0 + wn * 64 + ni * 16 + l16)] = acc[mi][ni][r];
}

// ---------------- flash attention (v11 = v10 + VALU cuts) ----------------
// v10 structure (best measured: 45.9 us) with two critical-path VALU cuts:
//  1. P pack via v_perm truncation (1 inst / 2 elems, bias cancels in P/l)
//  2. l-sum via MFMA(pf, ones) into a 4xf32x4 acc tile (kills 64 scalar
//     adds/iter + the epilogue butterfly; l is exact w.r.t. quantized P)
// Grid (bh, qt): XCD = bh%8 -> K/V L2-resident (verified: FETCH 74->13 MB).

__global__ __launch_bounds__(256, 2) void flash_attn(
    const bf16* __restrict__ QKV, const bf16* __restrict__ VT, bf16* __restrict__ att) {
    constexpr int LDK = 72;   // Ks stride: frag-read banks 4*(l16+quad) uniform
    constexpr int LDV = 136;  // Vs stride: b64 reads 2-way (free), writes 8-phase
    __shared__ __attribute__((aligned(16))) char smem[36864];
    bf16* Ks = (bf16*)smem;                // [128][72]  = 18432 B
    bf16* Vs = (bf16*)(smem + 18432);      // [64][136]  = 17408 B -> 35840
    float* Osc = (float*)smem;             // epilogue alias: 2 regions x 16 KB
    float* Lred = (float*)(smem + 32768);  // [4][64] floats

    const int tid = threadIdx.x, wid = tid >> 6, lane = tid & 63;
    const int quad = lane >> 4, l16 = lane & 15;
    const int qh = wid >> 1, kh = wid & 1;
    const int bh = blockIdx.x, qt = blockIdx.y;   // XCD = bh % 8 (L2-local K/V)
    const int b = bh >> 4, h = bh & 15;
    const int q0 = qt * 128;

    // ---- Q B-frags (resident): B[k=quad*8+j][n=l16] = Q[q][c] ----
    bf16x8 qf[4][2];
    {
        const bf16* qbase = QKV + (size_t)(b * 2048 + q0 + qh * 64 + l16) * 3072 + h * 64 + quad * 8;
#pragma unroll
        for (int mi = 0; mi < 4; ++mi)
#pragma unroll
            for (int ks = 0; ks < 2; ++ks)
                qf[mi][ks] = *(const bf16x8*)(qbase + (size_t)mi * 16 * 3072 + ks * 32);
    }

    // staging geometry (coalesced): K 128 rows x 128 B, V 64 rows x 256 B
    const int krow = tid >> 3, kcol = (tid & 7) * 8;   // 32 rows/pass, 4 passes
    const int vrow = tid >> 4, vcol = (tid & 15) * 8;  // 16 rows/pass, 4 passes
    const bf16* kg = QKV + (size_t)(b * 2048 + krow) * 3072 + 1024 + h * 64 + kcol;
    const bf16* vg = VT + (size_t)(h * 64 + vrow) * 4096 + b * 2048 + vcol;

    bf16x8 kr[4], vr[4];
#pragma unroll
    for (int p = 0; p < 4; ++p) {
        kr[p] = *(const bf16x8*)(kg + (size_t)(32 * p) * 3072);
        vr[p] = *(const bf16x8*)(vg + (size_t)(16 * p) * 4096);
    }

    const bf16 one = (bf16)1.0f;
    const bf16x8 onesf = (bf16x8){one, one, one, one, one, one, one, one};

    f32x4 o[4][4];
    f32x4 ls[4];
#pragma unroll
    for (int mi = 0; mi < 4; ++mi) {
        ls[mi] = (f32x4){0.f, 0.f, 0.f, 0.f};
#pragma unroll
        for (int ct = 0; ct < 4; ++ct) o[mi][ct] = (f32x4){0.f, 0.f, 0.f, 0.f};
    }

    for (int it = 0; it < 16; ++it) {
        // ---- stage prefetched regs -> LDS ----
#pragma unroll
        for (int p = 0; p < 4; ++p) {
            *(bf16x8*)&Ks[(32 * p + krow) * LDK + kcol] = kr[p];
            *(bf16x8*)&Vs[(16 * p + vrow) * LDV + vcol] = vr[p];
        }
        __syncthreads();

        // ---- prefetch next big-iter (hidden behind compute phase) ----
        if (it < 15) {
            const size_t ko = (size_t)(it + 1) * 128;
#pragma unroll
            for (int p = 0; p < 4; ++p) {
                kr[p] = *(const bf16x8*)(kg + (ko + 32 * p) * 3072);
                vr[p] = *(const bf16x8*)(vg + (size_t)(16 * p) * 4096 + ko);
            }
        }

        // ---- compute: wave's 64 keys as 2 pairs of 16-key groups ----
#pragma unroll
        for (int pr = 0; pr < 2; ++pr) {
            const int kb = kh * 64 + pr * 32;  // pair base (rel key)
            const bf16x8 kfA0 = *(const bf16x8*)&Ks[(kb + l16) * LDK + quad * 8];
            const bf16x8 kfA1 = *(const bf16x8*)&Ks[(kb + l16) * LDK + 32 + quad * 8];
            const bf16x8 kfB0 = *(const bf16x8*)&Ks[(kb + 16 + l16) * LDK + quad * 8];
            const bf16x8 kfB1 = *(const bf16x8*)&Ks[(kb + 16 + l16) * LDK + 32 + quad * 8];
            bf16x8 vf[4];
#pragma unroll
            for (int ct = 0; ct < 4; ++ct) {
                const bf16x4 lo = *(const bf16x4*)&Vs[(ct * 16 + l16) * LDV + kb + quad * 4];
                const bf16x4 hi = *(const bf16x4*)&Vs[(ct * 16 + l16) * LDV + kb + 16 + quad * 4];
                vf[ct] = (bf16x8){lo[0], lo[1], lo[2], lo[3], hi[0], hi[1], hi[2], hi[3]};
            }
#pragma unroll
            for (int mi = 0; mi < 4; ++mi) {
                f32x4 sA = (f32x4){0.f, 0.f, 0.f, 0.f};
                f32x4 sB = (f32x4){0.f, 0.f, 0.f, 0.f};
                sA = __builtin_amdgcn_mfma_f32_16x16x32_bf16(kfA0, qf[mi][0], sA, 0, 0, 0);
                sA = __builtin_amdgcn_mfma_f32_16x16x32_bf16(kfA1, qf[mi][1], sA, 0, 0, 0);
                sB = __builtin_amdgcn_mfma_f32_16x16x32_bf16(kfB0, qf[mi][0], sB, 0, 0, 0);
                sB = __builtin_amdgcn_mfma_f32_16x16x32_bf16(kfB1, qf[mi][1], sB, 0, 0, 0);

                const float pa0 = __builtin_amdgcn_exp2f(sA[0]);
                const float pa1 = __builtin_amdgcn_exp2f(sA[1]);
                const float pa2 = __builtin_amdgcn_exp2f(sA[2]);
                const float pa3 = __builtin_amdgcn_exp2f(sA[3]);
                const float pb0 = __builtin_amdgcn_exp2f(sB[0]);
                const float pb1 = __builtin_amdgcn_exp2f(sB[1]);
                const float pb2 = __builtin_amdgcn_exp2f(sB[2]);
                const float pb3 = __builtin_amdgcn_exp2f(sB[3]);

                // P A-frag via truncation pack (4 v_perm); lane = P[q=l16][j0..7]
                union { uint32_t u[4]; bf16x8 v; } pu;
                pu.u[0] = pktrunc(pa0, pa1);
                pu.u[1] = pktrunc(pa2, pa3);
                pu.u[2] = pktrunc(pb0, pb1);
                pu.u[3] = pktrunc(pb2, pb3);
                const bf16x8 pf = pu.v;
#pragma unroll
                for (int ct = 0; ct < 4; ++ct)
                    o[mi][ct] = __builtin_amdgcn_mfma_f32_16x16x32_bf16(pf, vf[ct], o[mi][ct], 0, 0, 0);
                // l-sum on the matrix pipe: D[q][*] = sum_k pf (all cols equal)
                ls[mi] = __builtin_amdgcn_mfma_f32_16x16x32_bf16(pf, onesf, ls[mi], 0, 0, 0);
            }
        }
        __syncthreads();
    }

    // ---- epilogue: publish l (already row-summed, q = mi*16+quad*4+r), ----
    // ---- cross-wave O reduce ----
    if (l16 == 0) {
#pragma unroll
        for (int mi = 0; mi < 4; ++mi)
#pragma unroll
            for (int r = 0; r < 4; ++r)
                Lred[wid * 64 + mi * 16 + quad * 4 + r] = ls[mi][r];
    }
    if (kh == 1) {
        float* dst = Osc + qh * 4096;
#pragma unroll
        for (int mi = 0; mi < 4; ++mi)
#pragma unroll
            for (int ct = 0; ct < 4; ++ct)
                *(f32x4*)(dst + (mi * 4 + ct) * 256 + lane * 4) = o[mi][ct];
    }
    __syncthreads();

    if (kh == 0) {
        const float* src = Osc + qh * 4096;
#pragma unroll
        for (int mi = 0; mi < 4; ++mi)
#pragma unroll
            for (int ct = 0; ct < 4; ++ct)
                o[mi][ct] += *(const f32x4*)(src + (mi * 4 + ct) * 256 + lane * 4);
#pragma unroll
        for (int mi = 0; mi < 4; ++mi)
#pragma unroll
            for (int r = 0; r < 4; ++r) {
                const int qrow = mi * 16 + quad * 4 + r;
                const float l = Lred[(qh * 2) * 64 + qrow] + Lred[(qh * 2 + 1) * 64 + qrow];
                const float inv = 1.0f / l;
                bf16* orow = att + (size_t)(b * 2048 + q0 + qh * 64 + qrow) * 1024 + h * 64 + l16;
#pragma unroll
                for (int ct = 0; ct < 4; ++ct)
                    orow[ct * 16] = (bf16)(o[mi][ct][r] * inv);
            }
    }
}

// ---------------- launch ----------------

extern "C" void kernel_launch(void* const* d_in, const int* in_sizes, int n_in,
                              void* d_out, int out_size, void* d_ws, size_t ws_size,
                              hipStream_t stream) {
    (void)in_sizes; (void)n_in; (void)out_size; (void)ws_size;
    const float* x  = (const float*)d_in[0];
    const float* Wq = (const float*)d_in[1];
    const float* Wk = (const float*)d_in[2];
    const float* Wv = (const float*)d_in[3];
    const float* Wo = (const float*)d_in[4];

    char* ws = (char*)d_ws;
    bf16* xb    = (bf16*)(ws);                             // 8 MB  [4096][1024]
    bf16* att   = xb;                                      // alias: xb dead after QKV GEMM
    bf16* WqkvT = (bf16*)(ws + (size_t)8  * 1024 * 1024);  // 6 MB [3072][1024]
    bf16* WoT   = (bf16*)(ws + (size_t)14 * 1024 * 1024);  // 2 MB [1024][1024]
    bf16* QKV   = (bf16*)(ws + (size_t)16 * 1024 * 1024);  // 24 MB [4096][3072] (V region unused)
    bf16* VT    = (bf16*)(ws + (size_t)40 * 1024 * 1024);  // 8 MB [1024][4096]
    // total 48 MB

    // x->bf16 (z=4) + all 4 weight transposes (z=0..3); Wq pre-scaled
    prep<<<dim3(32, 32, 5), 256, 0, stream>>>(x, Wq, Wk, Wv, Wo, xb, WqkvT, WoT);

    // QKV = xb @ [Wq|Wk|Wv] : M=4096 N=3072 K=1024 (768 blocks = 3/CU);
    // V-tiles stored transposed straight to VT (transpose_v fused away)
    gemm_bt<false><<<dim3(3072 / 128, 4096 / 128), 256, 0, stream>>>(
        xb, WqkvT, QKV, 4096, 3072, 1024, VT);

    // attention -> att[bs][hc]; grid (bh, qt) so XCD = bh%8 (L2-local K/V)
    flash_attn<<<dim3(32, 16), 256, 0, stream>>>(QKV, VT, att);

    // out = att @ Wo : M=4096 N=1024 K=1024, fp32 out, 64x128 tile (2 blk/CU)
    gemm_tm2<<<dim3(1024 / 128, 4096 / 64), 256, 0, stream>>>(
        att, WoT, (float*)d_out, 4096, 1024, 1024);
}